// Round 5
// baseline (491.117 us; speedup 1.0000x reference)
//
#include <hip/hip_runtime.h>
#include <hip/hip_bf16.h>
#include <math.h>

#define NB 32
#define NS 4096
#define ND 512
#define NU 128
#define RR 32
#define NCHUNK (NS / RR)   // 128

typedef __bf16 bf16x8 __attribute__((ext_vector_type(8)));
typedef unsigned short u16x8 __attribute__((ext_vector_type(8)));
typedef float f32x4 __attribute__((ext_vector_type(4)));
union FragCvt { u16x8 u; bf16x8 b; };

__device__ inline unsigned short f2bf(float x) {
  union { float f; unsigned u; } v; v.f = x;
  return (unsigned short)((v.u + 0x7FFFu + ((v.u >> 16) & 1u)) >> 16);
}
__device__ inline u16x8 pack8(float4 a, float4 b) {
  u16x8 r;
  r[0] = f2bf(a.x); r[1] = f2bf(a.y); r[2] = f2bf(a.z); r[3] = f2bf(a.w);
  r[4] = f2bf(b.x); r[5] = f2bf(b.y); r[6] = f2bf(b.z); r[7] = f2bf(b.w);
  return r;
}
// tanh(x) = 1 - 2/(e^{2x}+1); ~1e-6 abs err
__device__ inline float fast_tanh(float x) {
  float ex = __expf(2.f * x);
  return 1.f - 2.f / (ex + 1.f);
}

// ---- prep: qb[b][u] = q@W1 + b1 + b2 ; w2t[u][d] = bf16(W2[d][u]) ----
__global__ void prep(const float* __restrict__ q, const float* __restrict__ W1,
                     const float* __restrict__ b1, const float* __restrict__ b2,
                     const float* __restrict__ W2,
                     float* __restrict__ qb, unsigned short* __restrict__ w2t) {
  if (blockIdx.x < 16) {
    int idx = blockIdx.x * 256 + threadIdx.x;    // 4096 = 32*128
    int b = idx >> 7, u = idx & 127;
    float s = b1[u] + b2[u];
    const float* qr = q + b * ND;
    #pragma unroll 8
    for (int d = 0; d < ND; ++d) s += qr[d] * W1[d * NU + u];
    qb[idx] = s;
  } else {
    int idx = (blockIdx.x - 16) * 256 + threadIdx.x;  // 65536 = 128*512
    int u = idx >> 9, d = idx & 511;
    w2t[idx] = f2bf(W2[d * NU + u]);
  }
}

// ---- fused: one wave per 32-row chunk; no LDS, no barriers, pure dataflow ----
__global__ __launch_bounds__(256, 3) void fused_attn(
    const float* __restrict__ values,
    const float* __restrict__ qb,            // [NB][NU]
    const unsigned short* __restrict__ w2t,  // [NU][ND] bf16 bits
    const float* __restrict__ V,             // [NU]
    const float* __restrict__ bvp,           // [1]
    float* __restrict__ wout,                // [NB][NS] unnormalized e^s
    float* __restrict__ Cpart,               // [NB*NCHUNK][ND]
    float* __restrict__ Lacc)                // [NB] denom (zeroed)
{
  const int tid = threadIdx.x;
  const int wave = tid >> 6, lane = tid & 63;
  const int quad = lane >> 4, lidx = lane & 15;
  const int chunk = blockIdx.x * 4 + wave;   // [0, 4096)
  const int b = chunk >> 7;
  const int s0 = (chunk & 127) * RR;

  const float* vbase = values + ((size_t)b * NS + s0) * ND;

  f32x4 acc[2][8];
  #pragma unroll
  for (int mt = 0; mt < 2; ++mt)
    #pragma unroll
    for (int ut = 0; ut < 8; ++ut)
      acc[mt][ut] = (f32x4){0.f, 0.f, 0.f, 0.f};

  // A: lane(lidx,quad) reads row lidx (+16 for mt=1), cols quad*8 + kt*32 .. +8
  // -> one wave-load = 16 rows x 128 B = 32 fully-used cache lines (coalesced)
  const float* a0base = vbase + lidx * ND + quad * 8;
  const float* a1base = a0base + 16 * ND;
  // B: lane reads w2t row ut*16+lidx, same k window -> 16 x 64 B lines (L2-hot)
  const unsigned short* bbase = w2t + lidx * ND + quad * 8;

  #pragma unroll 2
  for (int kt = 0; kt < 16; ++kt) {
    const int ko = kt * 32;
    float4 a00 = *(const float4*)(a0base + ko);
    float4 a01 = *(const float4*)(a0base + ko + 4);
    float4 a10 = *(const float4*)(a1base + ko);
    float4 a11 = *(const float4*)(a1base + ko + 4);
    FragCvt af0; af0.u = pack8(a00, a01);
    FragCvt af1; af1.u = pack8(a10, a11);
    #pragma unroll
    for (int ut = 0; ut < 8; ++ut) {
      FragCvt bf; bf.u = *(const u16x8*)(bbase + ut * 16 * ND + ko);
      acc[0][ut] = __builtin_amdgcn_mfma_f32_16x16x32_bf16(af0.b, bf.b, acc[0][ut], 0, 0, 0);
      acc[1][ut] = __builtin_amdgcn_mfma_f32_16x16x32_bf16(af1.b, bf.b, acc[1][ut], 0, 0, 0);
    }
  }

  // ---- scores: tanh + dot V, reduce over u (intra-wave only) ----
  // acc[mt][ut][r] = v_proj for row (mt*16 + quad*4 + r), u = ut*16 + lidx
  float pr[2][4] = {{0.f,0.f,0.f,0.f},{0.f,0.f,0.f,0.f}};
  #pragma unroll
  for (int ut = 0; ut < 8; ++ut) {
    const int u = ut * 16 + lidx;
    const float qv = qb[b * NU + u];
    const float vv = V[u];
    #pragma unroll
    for (int mt = 0; mt < 2; ++mt)
      #pragma unroll
      for (int r = 0; r < 4; ++r)
        pr[mt][r] += fast_tanh(acc[mt][ut][r] + qv) * vv;
  }
  #pragma unroll
  for (int m = 1; m <= 8; m <<= 1)
    #pragma unroll
    for (int mt = 0; mt < 2; ++mt)
      #pragma unroll
      for (int r = 0; r < 4; ++r)
        pr[mt][r] += __shfl_xor(pr[mt][r], m, 64);

  // every lane of a quad-group now holds scores for its 8 rows (2mt x 4r)
  const float bv = *bvp;
  float e[2][4];
  #pragma unroll
  for (int mt = 0; mt < 2; ++mt)
    #pragma unroll
    for (int r = 0; r < 4; ++r)
      e[mt][r] = __expf(pr[mt][r] + bv);   // |score| <= ||V||_1 ~ 9: no max pass

  if (lidx == 0) {
    #pragma unroll
    for (int mt = 0; mt < 2; ++mt)
      #pragma unroll
      for (int r = 0; r < 4; ++r)
        wout[(size_t)b * NS + s0 + mt * 16 + quad * 4 + r] = e[mt][r];
  }

  // denominator: sum 8 per-lane rows, then across the 4 quad-groups
  float t = 0.f;
  #pragma unroll
  for (int mt = 0; mt < 2; ++mt)
    #pragma unroll
    for (int r = 0; r < 4; ++r)
      t += e[mt][r];
  t += __shfl_xor(t, 16, 64);
  t += __shfl_xor(t, 32, 64);
  if (lane == 0) atomicAdd(Lacc + b, t);

  // ---- context: c[d] = sum_r e_r * values[row r][d], rows L2-warm ----
  f32x4 c0 = (f32x4){0.f,0.f,0.f,0.f}, c1 = (f32x4){0.f,0.f,0.f,0.f};
  #pragma unroll
  for (int r = 0; r < 32; ++r) {
    const int mt = r >> 4, rg = r & 3, qsrc = (r >> 2) & 3;
    const float er = __shfl(e[mt][rg], qsrc * 16, 64);
    const float* vr = vbase + r * ND;
    c0 += er * *(const f32x4*)(vr + lane * 4);
    c1 += er * *(const f32x4*)(vr + lane * 4 + 256);
  }
  float* cp = Cpart + (size_t)chunk * ND;
  *(f32x4*)(cp + lane * 4) = c0;
  *(f32x4*)(cp + lane * 4 + 256) = c1;
}

// ---- finalize: tree-reduce context partials + normalize weights ----
__global__ void finalize(const float* __restrict__ Cpart, const float* __restrict__ Lacc,
                         float* __restrict__ out) {
  int idx = blockIdx.x * 256 + threadIdx.x;   // 147456 total
  if (idx < NB * ND) {
    int b = idx >> 9, d = idx & 511;
    const float* p = Cpart + (size_t)b * NCHUNK * ND + d;
    float a0 = 0.f, a1 = 0.f, a2 = 0.f, a3 = 0.f;
    #pragma unroll 4
    for (int c = 0; c < NCHUNK; c += 4) {
      a0 += p[(size_t)(c + 0) * ND];
      a1 += p[(size_t)(c + 1) * ND];
      a2 += p[(size_t)(c + 2) * ND];
      a3 += p[(size_t)(c + 3) * ND];
    }
    out[idx] = (a0 + a1 + a2 + a3) / Lacc[b];
  } else {
    int j = idx - NB * ND;
    int b = j >> 12;
    out[idx] = out[idx] / Lacc[b];
  }
}

extern "C" void kernel_launch(void* const* d_in, const int* in_sizes, int n_in,
                              void* d_out, int out_size, void* d_ws, size_t ws_size,
                              hipStream_t stream) {
  const float* query  = (const float*)d_in[0];
  const float* values = (const float*)d_in[1];
  const float* W1     = (const float*)d_in[2];
  const float* b1     = (const float*)d_in[3];
  const float* W2     = (const float*)d_in[4];
  const float* b2     = (const float*)d_in[5];
  const float* V      = (const float*)d_in[6];
  const float* bv     = (const float*)d_in[7];
  float* out = (float*)d_out;

  char* ws = (char*)d_ws;
  float* Cpart = (float*)ws;                                   // 8 MB
  float* Lacc  = (float*)(ws + 8388608);                       // 128 B (512 reserved)
  float* qbuf  = (float*)(ws + 8389120);                       // 16 KB
  unsigned short* w2t = (unsigned short*)(ws + 8405504);       // 128 KB

  hipMemsetAsync(Lacc, 0, 512, stream);

  prep<<<272, 256, 0, stream>>>(query, W1, b1, b2, W2, qbuf, w2t);
  fused_attn<<<NB * NCHUNK / 4, 256, 0, stream>>>(values, qbuf, w2t, V, bv,
                                                  out + NB * ND, Cpart, Lacc);
  finalize<<<576, 256, 0, stream>>>(Cpart, Lacc, out);
}